// Round 1
// baseline (440.924 us; speedup 1.0000x reference)
//
#include <hip/hip_runtime.h>
#include <hip/hip_fp16.h>
#include <cstdint>
#include <cstddef>

// QLinear: per-token int8 quant -> int8 GEMM (MFMA 32x32x32 i8) -> dequant+bias
// M=8192, K=4096, N=4096.  weight_q arrives as int32 (harness promotes ints),
// bias fp16 promoted to fp32, out as fp32.
//
// R1 changes vs baseline (206us gemm, MfmaUtil 29%, 5.0e7 LDS conflicts):
//  - GEMM: BK 64->128 (128B LDS rows), XOR swizzle chunk^=(row&7) applied to
//    global SOURCE of global_load_lds + ds_read addr (LDS dest stays linear),
//    double-buffered 2-phase pipeline (stage t+1 in flight during compute t),
//    XCD-aware bijective block swizzle.
//  - prep: quant_x and pack_w merged into one dispatch; per-element fdiv ->
//    one fdiv + reciprocal multiply.

#define MDIM 8192
#define KDIM 4096
#define NDIM 4096

#define BM 128
#define BN 128
#define BK 128
#define NT (KDIM / BK)  // 32 K-steps

typedef int v4i  __attribute__((ext_vector_type(4)));
typedef int v16i __attribute__((ext_vector_type(16)));

__device__ __forceinline__ void load_lds_16(const void* g, void* l) {
  __builtin_amdgcn_global_load_lds((const __attribute__((address_space(1))) void*)g,
                                   (__attribute__((address_space(3))) void*)l,
                                   16, 0, 0);
}

// ---------------- fused prep: per-token quant (blocks 0..M-1) + weight repack ----
extern "C" __global__ __launch_bounds__(256)
void qlin_prep(const float* __restrict__ x, int8_t* __restrict__ xq,
               float* __restrict__ xs, const int* __restrict__ w32,
               int8_t* __restrict__ w8) {
  const int t = threadIdx.x;
  if (blockIdx.x >= MDIM) {
    // weight int32 -> int8 repack: 1024 int32 per block
    const size_t idx = (size_t)(blockIdx.x - MDIM) * 256 + t;
    const int4 w = ((const int4*)w32)[idx];
    ((int*)w8)[idx] = (w.x & 0xff) | ((w.y & 0xff) << 8) |
                      ((w.z & 0xff) << 16) | ((w.w & 0xff) << 24);
    return;
  }
  const int row = blockIdx.x;
  const float4* xr = (const float4*)(x + (size_t)row * KDIM);
  float4 v[4];
  float amax = 0.f;
#pragma unroll
  for (int i = 0; i < 4; ++i) {
    v[i] = xr[t + 256 * i];
    amax = fmaxf(amax, fmaxf(fmaxf(fabsf(v[i].x), fabsf(v[i].y)),
                             fmaxf(fabsf(v[i].z), fabsf(v[i].w))));
  }
#pragma unroll
  for (int off = 32; off > 0; off >>= 1)
    amax = fmaxf(amax, __shfl_xor(amax, off, 64));
  __shared__ float smax[4];
  if ((t & 63) == 0) smax[t >> 6] = amax;
  __syncthreads();
  amax = fmaxf(fmaxf(smax[0], smax[1]), fmaxf(smax[2], smax[3]));
  const float scale = fmaxf(amax, 1e-7f) / 127.0f;  // stored scale: exact ref math
  const float inv   = 1.0f / scale;  // one division; mul below (flips are rare
                                     // and bounded ~0.14 on out, inside absmax)
  if (t == 0) xs[row] = scale;
  int* outp = (int*)(xq + (size_t)row * KDIM);
#pragma unroll
  for (int i = 0; i < 4; ++i) {
    int q0 = (int)rintf(v[i].x * inv);
    int q1 = (int)rintf(v[i].y * inv);
    int q2 = (int)rintf(v[i].z * inv);
    int q3 = (int)rintf(v[i].w * inv);
    q0 = min(127, max(-128, q0));
    q1 = min(127, max(-128, q1));
    q2 = min(127, max(-128, q2));
    q3 = min(127, max(-128, q3));
    outp[t + 256 * i] = (q0 & 0xff) | ((q1 & 0xff) << 8) |
                        ((q2 & 0xff) << 16) | ((q3 & 0xff) << 24);
  }
}

// ---------------- int8 GEMM, 128x128 tile, BK=128, double-buffered 2-phase ----
// 4 waves; wave (wr,wc) owns a 64x64 quadrant as 2x2 tiles of 32x32.
// A = xq [M,K] row-major; B = w8 [N,K] row-major (K-contiguous).
// LDS tile layout: [row][128B], physical 16B-chunk c holds logical K-chunk
// c ^ (row&7).  Stager pre-swizzles the GLOBAL source; LDS dest stays linear
// (global_load_lds requirement).  ds_read applies the same XOR -> lanes spread
// over all 8 bank-quads (conflict-free b128).
extern "C" __global__ __launch_bounds__(256, 2)
void qlin_gemm(const int8_t* __restrict__ Aq, const int8_t* __restrict__ Bq,
               const float* __restrict__ xs, const float* __restrict__ ws,
               const float* __restrict__ bias, float* __restrict__ out) {
  __shared__ int8_t As[2][BM * BK];  // 2 x 16 KB
  __shared__ int8_t Bs[2][BN * BK];  // 2 x 16 KB
  const int tid  = threadIdx.x;
  const int lane = tid & 63;
  const int wave = tid >> 6;
  const int wr   = wave >> 1;
  const int wc   = wave & 1;

  // XCD-aware bijective swizzle: 2048 blocks, 8 XCDs, 256 consecutive each
  const int id  = blockIdx.x;
  const int swz = (id & 7) * 256 + (id >> 3);
  const int bx  = swz & 31;   // N/BN = 32
  const int by  = swz >> 5;   // M/BM = 64
  const int m0  = by * BM;
  const int n0  = bx * BN;

  const int8_t* Ab = Aq + (size_t)m0 * KDIM;
  const int8_t* Bb = Bq + (size_t)n0 * KDIM;

  // staging map: instruction `it` covers chunks q = (wave*4+it)*64 + lane;
  // row = q>>3 (0..127), chunk c = q&7.  LDS dst = q*16 (linear, wave-uniform
  // base + lane*16).  Global src K-chunk = c ^ (row&7)  [XOR swizzle source].
  int srow[4], scsw[4], sdst[4];
#pragma unroll
  for (int it = 0; it < 4; ++it) {
    const int q = (wave * 4 + it) * 64 + lane;
    const int rr = q >> 3;
    const int c  = q & 7;
    srow[it] = rr;
    scsw[it] = ((c ^ (rr & 7)) << 4);
    sdst[it] = q * 16;
  }

  // fragment-read LDS byte offsets (logical kbyte = ks*32 + hi*16, kc=ks*2+hi)
  const int r  = lane & 31;
  const int hi = lane >> 5;
  const int rx = r & 7;
  int aoff[2][4], boff[2][4];
#pragma unroll
  for (int i = 0; i < 2; ++i)
#pragma unroll
    for (int ks = 0; ks < 4; ++ks) {
      const int kphys = ((ks * 2 + hi) ^ rx) << 4;
      aoff[i][ks] = (wr * 64 + i * 32 + r) * BK + kphys;
      boff[i][ks] = (wc * 64 + i * 32 + r) * BK + kphys;
    }

  v16i acc[2][2];
#pragma unroll
  for (int i = 0; i < 2; ++i)
#pragma unroll
    for (int j = 0; j < 2; ++j)
#pragma unroll
      for (int rg = 0; rg < 16; ++rg) acc[i][j][rg] = 0;

  auto STAGE = [&](int k0, int buf) {
#pragma unroll
    for (int it = 0; it < 4; ++it) {
      load_lds_16(Ab + (size_t)srow[it] * KDIM + (k0 + scsw[it]), &As[buf][sdst[it]]);
      load_lds_16(Bb + (size_t)srow[it] * KDIM + (k0 + scsw[it]), &Bs[buf][sdst[it]]);
    }
  };

  STAGE(0, 0);
  __syncthreads();  // drain each wave's own loads + barrier -> buf0 ready

  int buf = 0;
  for (int t = 0; t < NT; ++t) {
    if (t + 1 < NT) STAGE((t + 1) * BK, buf ^ 1);  // async, in flight during MFMAs
#pragma unroll
    for (int ks = 0; ks < 4; ++ks) {
      v4i a[2], b[2];
#pragma unroll
      for (int i = 0; i < 2; ++i) a[i] = *(const v4i*)(&As[buf][aoff[i][ks]]);
#pragma unroll
      for (int j = 0; j < 2; ++j) b[j] = *(const v4i*)(&Bs[buf][boff[j][ks]]);
#pragma unroll
      for (int i = 0; i < 2; ++i)
#pragma unroll
        for (int j = 0; j < 2; ++j)
          acc[i][j] = __builtin_amdgcn_mfma_i32_32x32x32_i8(a[i], b[j], acc[i][j], 0, 0, 0);
    }
    __syncthreads();  // drains vmcnt (next-tile loads landed) + everyone done
                      // reading buf[cur]; single drain per K-step, after compute
    buf ^= 1;
  }

  // epilogue: C/D layout col=lane&31, row=(reg&3)+8*(reg>>2)+4*(lane>>5)
  // (verbatim from verified baseline)
  const int col = lane & 31;
  const int rb  = hi * 4;
#pragma unroll
  for (int j = 0; j < 2; ++j) {
    const int gc = n0 + wc * 64 + j * 32 + col;
    const float wsv = ws[gc];
    const float bv  = bias[gc];
#pragma unroll
    for (int i = 0; i < 2; ++i) {
      const int grb = m0 + wr * 64 + i * 32 + rb;
#pragma unroll
      for (int reg = 0; reg < 16; ++reg) {
        const int gr = grb + (reg & 3) + 8 * (reg >> 2);
        float t2 = (float)acc[i][j][reg] * xs[gr];  // (acc * x_scale)
        t2 = t2 * wsv + bv;                         // * w_scale + bias
        out[(size_t)gr * NDIM + gc] = __half2float(__float2half(t2));
      }
    }
  }
}

extern "C" void kernel_launch(void* const* d_in, const int* in_sizes, int n_in,
                              void* d_out, int out_size, void* d_ws, size_t ws_size,
                              hipStream_t stream) {
  const float* x      = (const float*)d_in[0];
  const int*   wq32   = (const int*)d_in[1];    // int8 promoted to int32 by harness
  const float* wscale = (const float*)d_in[2];
  const float* bias   = (const float*)d_in[3];  // fp16 promoted to fp32 by harness
  float*       out    = (float*)d_out;

  int8_t* xq = (int8_t*)d_ws;                                    // M*K = 32 MiB
  int8_t* w8 = (int8_t*)d_ws + (size_t)MDIM * KDIM;              // N*K = 16 MiB
  float*  xs = (float*)((int8_t*)d_ws + (size_t)MDIM * KDIM + (size_t)NDIM * KDIM);

  // fused prep: blocks [0, M) quantize rows; blocks [M, M + N*K/1024) repack W
  qlin_prep<<<MDIM + (NDIM * KDIM / 4) / 256, 256, 0, stream>>>(x, xq, xs, wq32, w8);
  qlin_gemm<<<(MDIM / BM) * (NDIM / BN), 256, 0, stream>>>(xq, w8, xs, wscale, bias, out);
}

// Round 2
// 422.702 us; speedup vs baseline: 1.0431x; 1.0431x over previous
//
#include <hip/hip_runtime.h>
#include <hip/hip_fp16.h>
#include <cstdint>
#include <cstddef>

// QLinear: per-token int8 quant -> int8 GEMM (MFMA 32x32x32 i8) -> dequant+bias
// M=8192, K=4096, N=4096.
//
// R2 changes vs R1 (gemm 199us, MfmaUtil 30%, conflicts at b128 floor):
//  - GEMM geometry: 256x256 tile, BK=128, 512 thr / 8 waves (2Mx4N), each wave
//    owns 128x64 (4x2 tiles of 32x32) -> 32 MFMA per wave per K-step (2x R1),
//    2x compute per staged byte.  LDS 128KB double-buffered (template-precedent).
//  - dropped XCD swizzle (R1: +124MB FETCH, no time change; working set L3-fit).
//  - sync structure UNCHANGED from verified R1 (2-phase dbuf, one barrier/step,
//    XOR swizzle c^=(row&7) on global source + ds_read addr, linear LDS dest).

#define MDIM 8192
#define KDIM 4096
#define NDIM 4096

#define BM 256
#define BN 256
#define BK 128
#define NT (KDIM / BK)  // 32 K-steps

typedef int v4i  __attribute__((ext_vector_type(4)));
typedef int v16i __attribute__((ext_vector_type(16)));

__device__ __forceinline__ void load_lds_16(const void* g, void* l) {
  __builtin_amdgcn_global_load_lds((const __attribute__((address_space(1))) void*)g,
                                   (__attribute__((address_space(3))) void*)l,
                                   16, 0, 0);
}

// ---------------- fused prep: per-token quant (blocks 0..M-1) + weight repack ----
extern "C" __global__ __launch_bounds__(256)
void qlin_prep(const float* __restrict__ x, int8_t* __restrict__ xq,
               float* __restrict__ xs, const int* __restrict__ w32,
               int8_t* __restrict__ w8) {
  const int t = threadIdx.x;
  if (blockIdx.x >= MDIM) {
    const size_t idx = (size_t)(blockIdx.x - MDIM) * 256 + t;
    const int4 w = ((const int4*)w32)[idx];
    ((int*)w8)[idx] = (w.x & 0xff) | ((w.y & 0xff) << 8) |
                      ((w.z & 0xff) << 16) | ((w.w & 0xff) << 24);
    return;
  }
  const int row = blockIdx.x;
  const float4* xr = (const float4*)(x + (size_t)row * KDIM);
  float4 v[4];
  float amax = 0.f;
#pragma unroll
  for (int i = 0; i < 4; ++i) {
    v[i] = xr[t + 256 * i];
    amax = fmaxf(amax, fmaxf(fmaxf(fabsf(v[i].x), fabsf(v[i].y)),
                             fmaxf(fabsf(v[i].z), fabsf(v[i].w))));
  }
#pragma unroll
  for (int off = 32; off > 0; off >>= 1)
    amax = fmaxf(amax, __shfl_xor(amax, off, 64));
  __shared__ float smax[4];
  if ((t & 63) == 0) smax[t >> 6] = amax;
  __syncthreads();
  amax = fmaxf(fmaxf(smax[0], smax[1]), fmaxf(smax[2], smax[3]));
  const float scale = fmaxf(amax, 1e-7f) / 127.0f;  // stored scale: exact ref math
  const float inv   = 1.0f / scale;
  if (t == 0) xs[row] = scale;
  int* outp = (int*)(xq + (size_t)row * KDIM);
#pragma unroll
  for (int i = 0; i < 4; ++i) {
    int q0 = (int)rintf(v[i].x * inv);
    int q1 = (int)rintf(v[i].y * inv);
    int q2 = (int)rintf(v[i].z * inv);
    int q3 = (int)rintf(v[i].w * inv);
    q0 = min(127, max(-128, q0));
    q1 = min(127, max(-128, q1));
    q2 = min(127, max(-128, q2));
    q3 = min(127, max(-128, q3));
    outp[t + 256 * i] = (q0 & 0xff) | ((q1 & 0xff) << 8) |
                        ((q2 & 0xff) << 16) | ((q3 & 0xff) << 24);
  }
}

// ---------------- int8 GEMM, 256x256 tile, BK=128, 8 waves, 2-phase dbuf ----
// A = xq [M,K] row-major; B = w8 [N,K] row-major (K-contiguous).
// Wave (wr,wc): wr=wave>>2 owns rows wr*128..+128; wc=wave&3 owns cols wc*64..+64.
// LDS tile [row][128B]; physical 16B-chunk c holds logical chunk c^(row&7).
extern "C" __global__ __launch_bounds__(512, 2)
void qlin_gemm(const int8_t* __restrict__ Aq, const int8_t* __restrict__ Bq,
               const float* __restrict__ xs, const float* __restrict__ ws,
               const float* __restrict__ bias, float* __restrict__ out) {
  __shared__ int8_t As[2][BM * BK];  // 2 x 32 KB
  __shared__ int8_t Bs[2][BN * BK];  // 2 x 32 KB
  const int tid  = threadIdx.x;
  const int lane = tid & 63;
  const int wave = tid >> 6;   // 0..7
  const int wr   = wave >> 2;  // 0..1  (128-row half)
  const int wc   = wave & 3;   // 0..3  (64-col quarter)

  const int m0 = blockIdx.y * BM;
  const int n0 = blockIdx.x * BN;

  const int8_t* Ab = Aq + (size_t)m0 * KDIM;
  const int8_t* Bb = Bq + (size_t)n0 * KDIM;

  // staging map: instruction `it` covers chunk-index q = (wave*4+it)*64 + lane,
  // q in [0,2048) covering 256 rows x 8 chunks.  row=q>>3, c=q&7.
  // LDS dst = q*16 (linear, wave-uniform base + lane*16).
  // Global src K-chunk = c ^ (row&7)  [XOR swizzle applied at the source].
  int srow[4], scsw[4], sdst[4];
#pragma unroll
  for (int it = 0; it < 4; ++it) {
    const int q  = (wave * 4 + it) * 64 + lane;
    const int rr = q >> 3;
    const int c  = q & 7;
    srow[it] = rr;
    scsw[it] = ((c ^ (rr & 7)) << 4);
    sdst[it] = q * 16;
  }

  // fragment-read LDS byte offsets: logical 16B-chunk kc = ks*2 + hi
  const int r  = lane & 31;
  const int hi = lane >> 5;
  const int rx = r & 7;
  int aoff[4][4], boff[2][4];
#pragma unroll
  for (int ks = 0; ks < 4; ++ks) {
    const int kphys = ((ks * 2 + hi) ^ rx) << 4;
#pragma unroll
    for (int i = 0; i < 4; ++i)
      aoff[i][ks] = (wr * 128 + i * 32 + r) * BK + kphys;
#pragma unroll
    for (int j = 0; j < 2; ++j)
      boff[j][ks] = (wc * 64 + j * 32 + r) * BK + kphys;
  }

  v16i acc[4][2];
#pragma unroll
  for (int i = 0; i < 4; ++i)
#pragma unroll
    for (int j = 0; j < 2; ++j)
#pragma unroll
      for (int rg = 0; rg < 16; ++rg) acc[i][j][rg] = 0;

  auto STAGE = [&](int k0, int buf) {
#pragma unroll
    for (int it = 0; it < 4; ++it) {
      load_lds_16(Ab + (size_t)srow[it] * KDIM + (k0 + scsw[it]), &As[buf][sdst[it]]);
      load_lds_16(Bb + (size_t)srow[it] * KDIM + (k0 + scsw[it]), &Bs[buf][sdst[it]]);
    }
  };

  STAGE(0, 0);
  __syncthreads();  // implicit vmcnt(0) drain + barrier -> buf0 ready

  int buf = 0;
  for (int t = 0; t < NT; ++t) {
    if (t + 1 < NT) STAGE((t + 1) * BK, buf ^ 1);  // in flight during MFMAs
#pragma unroll
    for (int ks = 0; ks < 4; ++ks) {
      v4i a[4], b[2];
#pragma unroll
      for (int i = 0; i < 4; ++i) a[i] = *(const v4i*)(&As[buf][aoff[i][ks]]);
#pragma unroll
      for (int j = 0; j < 2; ++j) b[j] = *(const v4i*)(&Bs[buf][boff[j][ks]]);
#pragma unroll
      for (int i = 0; i < 4; ++i)
#pragma unroll
        for (int j = 0; j < 2; ++j)
          acc[i][j] = __builtin_amdgcn_mfma_i32_32x32x32_i8(a[i], b[j], acc[i][j], 0, 0, 0);
    }
    __syncthreads();  // single drain per K-step, after compute
    buf ^= 1;
  }

  // epilogue: C/D layout col=lane&31, row=(reg&3)+8*(reg>>2)+4*(lane>>5)
  const int col = lane & 31;
  const int rb  = hi * 4;
#pragma unroll
  for (int j = 0; j < 2; ++j) {
    const int gc = n0 + wc * 64 + j * 32 + col;
    const float wsv = ws[gc];
    const float bv  = bias[gc];
#pragma unroll
    for (int i = 0; i < 4; ++i) {
      const int grb = m0 + wr * 128 + i * 32 + rb;
#pragma unroll
      for (int reg = 0; reg < 16; ++reg) {
        const int gr = grb + (reg & 3) + 8 * (reg >> 2);
        float t2 = (float)acc[i][j][reg] * xs[gr];  // (acc * x_scale)
        t2 = t2 * wsv + bv;                         // * w_scale + bias
        out[(size_t)gr * NDIM + gc] = __half2float(__float2half(t2));
      }
    }
  }
}

extern "C" void kernel_launch(void* const* d_in, const int* in_sizes, int n_in,
                              void* d_out, int out_size, void* d_ws, size_t ws_size,
                              hipStream_t stream) {
  const float* x      = (const float*)d_in[0];
  const int*   wq32   = (const int*)d_in[1];    // int8 promoted to int32 by harness
  const float* wscale = (const float*)d_in[2];
  const float* bias   = (const float*)d_in[3];  // fp16 promoted to fp32 by harness
  float*       out    = (float*)d_out;

  int8_t* xq = (int8_t*)d_ws;                                    // M*K = 32 MiB
  int8_t* w8 = (int8_t*)d_ws + (size_t)MDIM * KDIM;              // N*K = 16 MiB
  float*  xs = (float*)((int8_t*)d_ws + (size_t)MDIM * KDIM + (size_t)NDIM * KDIM);

  qlin_prep<<<MDIM + (NDIM * KDIM / 4) / 256, 256, 0, stream>>>(x, xq, xs, wq32, w8);
  qlin_gemm<<<dim3(NDIM / BN, MDIM / BM), 512, 0, stream>>>(xq, w8, xs, wscale, bias, out);
}